// Round 11
// baseline (400.340 us; speedup 1.0000x reference)
//
#include <hip/hip_runtime.h>
#include <math.h>

#define NT 256
#define NW 4

typedef __attribute__((ext_vector_type(8))) short short8;
typedef __attribute__((ext_vector_type(4))) float f32x4;

// ---- LDS arena byte offsets (total 53,264 B; 3 blocks/CU) ----
#define U_OFF    0        // 64 f32
#define IT_OFF   256      // 64 f32
#define B1_OFF   512      // 32 f32
#define RB_OFF   640      // 160 f32
#define PW_OFF   1280     // 32 f32
#define PBI_OFF  1408     // 1 f32
#define ZP_OFF   1424     // 64 B zero page (predicated out-of-range reads land here)
#define X1_OFF   1536     // bf16 [17][32][32] stride 2064 -> 35088 (two-half strip of conv1 out)
#define X1_STR   2064
#define X2_OFF   36624    // bf16 [16][16][32] stride 1040 -> 16640 -> end 53264
#define X2_STR   1040
#define X3_OFF   X1_OFF   // alias over X1 (dead after conv2b): bf16 [8][8][32] stride 528
#define X3_STR   528
#define X4_OFF   (X1_OFF + 4224)   // bf16 [4][4][32] stride 272 -> 1088
#define X4_STR   272
#define X5_OFF   (X1_OFF + 5312)   // bf16 [2][2][32] stride 144 -> 288
#define X5_STR   144
#define X6_OFF   (X1_OFF + 5600)   // 32 f32 = 128
#define SMEM_BYTES 53264
// R11: T staging (18.4 KB) deleted -> P2 threads compute their T-slice directly
// from global w1 (2 KB, L2-resident). 53,264 x 3 = 159,792 <= 160 KB LDS -> 3
// blocks/CU; launch_bounds(256,3) caps VGPR ~170 (R8 lesson: VGPR pool, not
// LDS, gated 2-block residency at 512 threads; R7 lesson: too-tight cap spills).
// All X accesses swizzled: byte_bit4 ^= buffer_row_bit3; OOB taps -> zero page.

__device__ __forceinline__ unsigned short f2bf(float f) {   // RNE f32->bf16
    unsigned int x = __float_as_uint(f);
    x += 0x7fffu + ((x >> 16) & 1u);
    return (unsigned short)(x >> 16);
}

// B-frags for mfma_f32_16x16x32_bf16 (VERIFIED mapping, Round 2):
// lane l: col n=l&15 (co = nt*16+n), k = (l>>4)*8 + e.  ws: bf16 [L][tap][co][ci].
__device__ __forceinline__ void loadB16(short8 bfr[16], const unsigned short* __restrict__ wsbf,
                                        const float* __restrict__ rwg, int useWs,
                                        int L, int co, int g) {
    if (useWs) {
        const unsigned short* base = wsbf + L * 16384 + co * 32 + g * 8;
#pragma unroll
        for (int tap = 0; tap < 16; ++tap)
            bfr[tap] = *(const short8*)(base + tap * 1024);
    } else {  // fallback: gather f32 weights from rwg [L][co][ci][tap], convert in regs
#pragma unroll
        for (int tap = 0; tap < 16; ++tap) {
            union { short8 s; unsigned short u[8]; } cv;
#pragma unroll
            for (int e = 0; e < 8; ++e)
                cv.u[e] = f2bf(rwg[((L * 32 + co) * 32 + g * 8 + e) * 16 + tap]);
            bfr[tap] = cv.s;
        }
    }
}

// One conv layer as 16 tap-GEMMs via mfma_f32_16x16x32_bf16 (Round-2-verified
// mappings). Output PH x QW spatial block (rows offset by p0), m = q*PH + p.
// Input: logical NIN x NIN halo-free tensor; buffer row = logical row - shift.
// Out-of-range taps read the zero page. All addrs swizzled: bit4 ^= row bit3.
template<int PH, int QW, int NIN, int INS, int OUTS, bool LAST>
__device__ __forceinline__ void convL(char* smb, int inOff, int outOff,
                                      const short8 bfr[16], float bias,
                                      int p0, int shift) {
    const int t = threadIdx.x;
    const int w = t >> 6, l = t & 63;
    const int n = l & 15, g = l >> 4, nt = w & 1;
    constexpr int M = PH * QW;
    constexpr int MT = (M + 15) / 16;
    for (int tile = w; tile < 2 * MT; tile += NW) {   // step NW (even) keeps tile&1 == nt
        const int mt = tile >> 1;
        f32x4 acc = {bias, bias, bias, bias};
        const int m = mt * 16 + (l & 15);
        const int mm = (m < M) ? m : 0;
        const int p = mm % PH, q = mm / PH;
#pragma unroll
        for (int a = 0; a < 4; ++a)
#pragma unroll
            for (int dj = 0; dj < 4; ++dj) {
                const int row = 2 * (p0 + p) + a - 1;       // logical coords
                const int col = 2 * q + dj - 1;
                const bool ok = (m < M) && ((unsigned)row < (unsigned)NIN)
                                        && ((unsigned)col < (unsigned)NIN);
                const int rb = row - shift;                  // buffer row
                unsigned addr = (unsigned)(inOff + rb * INS + col * 64 + g * 16);
                addr ^= (unsigned)(((rb >> 3) & 1) << 4);
                addr = ok ? addr : (unsigned)(ZP_OFF + g * 16);
                short8 af = *(const short8*)(smb + addr);
                acc = __builtin_amdgcn_mfma_f32_16x16x32_bf16(af, bfr[a * 4 + dj], acc, 0, 0, 0);
            }
#pragma unroll
        for (int vi = 0; vi < 4; ++vi) {                     // D: col=l&15, row=g*4+vi
            const int mo = mt * 16 + g * 4 + vi;
            if (mo < M) {
                const float v = fmaxf(acc[vi], 0.f);
                if constexpr (LAST) {                        // M==1: only mo==0 lands here
                    *(float*)(smb + outOff + (nt * 16 + n) * 4) = v;
                } else {
                    const int po = mo % PH + p0, qo = mo / PH;
                    unsigned addr = (unsigned)(outOff + po * OUTS + qo * 64 + (nt * 16 + n) * 2);
                    addr ^= (unsigned)(((po >> 3) & 1) << 4);
                    *(unsigned short*)(smb + addr) = f2bf(v);
                }
            }
        }
    }
}

// pre-convert rest_w (f32 [L][co][ci][a][dj]) -> d_ws bf16 [L][tap][co][ci]
__global__ void preconv_w(const float* __restrict__ rwg, unsigned short* __restrict__ wsbf) {
    int idx = blockIdx.x * 256 + threadIdx.x;
    if (idx < 81920) {
        int ci = idx & 31, co = (idx >> 5) & 31, tap = (idx >> 10) & 15, L = idx >> 14;
        wsbf[idx] = f2bf(rwg[(((L * 32 + co) * 32 + ci) << 4) + tap]);
    }
}

__global__ void __launch_bounds__(NT, 3)
convncf_main(const int* __restrict__ user, const int* __restrict__ item_pos,
             const int* __restrict__ item_neg,
             const float* __restrict__ uemb, const float* __restrict__ iemb,
             const float* __restrict__ w1g, const float* __restrict__ b1g,
             const float* __restrict__ rwg, const float* __restrict__ rbg,
             const float* __restrict__ pwg, const float* __restrict__ pbg,
             const unsigned short* __restrict__ wsbf, int useWs,
             float* __restrict__ out, int B)
{
    extern __shared__ char smb[];
    float* smf = (float*)smb;
    const int t = threadIdx.x, w = t >> 6, l = t & 63;
    const int co = ((t >> 6) & 1) * 16 + (t & 15);   // this thread's output channel
    const int g = l >> 4;
    const int s = blockIdx.x, branch = blockIdx.y;
    const int uidx = user[s];
    const int iidx = branch ? item_neg[s] : item_pos[s];

    short8 bfr[16];
    loadB16(bfr, wsbf, rwg, useWs, 0, co, g);   // conv2 weights: hide under P0-P2a

    // ---- P0: consts + embeddings + zero page (strided loop: 353 items) ----
    for (int i = t; i < 353; i += NT) {
        if (i < 64)       smf[U_OFF/4 + i]        = uemb[(long)uidx * 64 + i];
        else if (i < 128) smf[IT_OFF/4 + i - 64]  = iemb[(long)iidx * 64 + i - 64];
        else if (i < 160) smf[B1_OFF/4 + i - 128] = b1g[i - 128];
        else if (i < 320) smf[RB_OFF/4 + i - 160] = rbg[i - 160];
        else if (i < 352) smf[PW_OFF/4 + i - 320] = pwg[i - 320];
        else              smf[PBI_OFF/4] = pbg[0];
    }
    if (t < 4) *(float4*)(smb + ZP_OFF + t * 16) = make_float4(0.f, 0.f, 0.f, 0.f);
    __syncthreads();

    // ---- P2+conv2, two half-strips. Thread owns (jp, cgp); its T-slice
    //      tval[a][e] = sum_dj w1[cgp*8+e][a][dj] * it_pad[2jp-1+dj] is computed
    //      DIRECTLY from global w1 (L2-resident) — no T staging in LDS at all.
    //      u reads are wave-uniform broadcasts; rows looped in registers. ----
    {
        const int pi = t & 127;
        const int cgp = pi & 3, jp = pi >> 2;        // this thread's (col j, chan group)
        const int rlh = t >> 7;                      // row-half: 0 -> rl 0..8, 1 -> rl 9..16
        const int rl0 = rlh ? 9 : 0;
        const int rl1 = rlh ? 17 : 9;

        float itv[4];                                // item taps with pad guards
#pragma unroll
        for (int dj = 0; dj < 4; ++dj) {
            const int c = 2 * jp - 1 + dj;
            itv[dj] = (c >= 0 && c < 64) ? smf[IT_OFF/4 + c] : 0.f;
        }
        float tval[4][8];                            // T[a][jp][cgp*8+e], in regs
#pragma unroll
        for (int e = 0; e < 8; ++e) {
            const float* wp = w1g + (cgp * 8 + e) * 16;
#pragma unroll
            for (int a = 0; a < 4; ++a) {
                const float4 wv = *(const float4*)(wp + a * 4);
                float v = wv.x * itv[0];
                v = fmaf(wv.y, itv[1], v);
                v = fmaf(wv.z, itv[2], v);
                v = fmaf(wv.w, itv[3], v);
                tval[a][e] = v;
            }
        }
        float bb[8];
        {
            const float* b1p = smf + B1_OFF/4 + cgp * 8;
#pragma unroll
            for (int e = 0; e < 8; ++e) bb[e] = b1p[e];
        }

#pragma unroll 1
        for (int h = 0; h < 2; ++h) {
            const int shift = 15 * h;
            for (int rl = rl0; rl < rl1; ++rl) {
                const int r = rl + shift;
                float acc[8];
#pragma unroll
                for (int e = 0; e < 8; ++e) acc[e] = bb[e];
#pragma unroll
                for (int a = 0; a < 4; ++a) {
                    const int m = 2 * r - 1 + a;
                    const float uv = (m >= 0 && m < 64) ? smf[U_OFF/4 + m] : 0.f;
#pragma unroll
                    for (int e = 0; e < 8; ++e)
                        acc[e] = fmaf(uv, tval[a][e], acc[e]);
                }
                union { short8 sv; unsigned short u[8]; } cv;
#pragma unroll
                for (int e = 0; e < 8; ++e) cv.u[e] = f2bf(fmaxf(acc[e], 0.f));
                unsigned addr = (unsigned)(X1_OFF + rl * X1_STR + jp * 64 + cgp * 16);
                addr ^= (unsigned)(((rl >> 3) & 1) << 4);
                *(short8*)(smb + addr) = cv.sv;
            }
            __syncthreads();

            // conv2(h): output rows 8h..8h+7, all 16 cols
            convL<8, 16, 32, X1_STR, X2_STR, false>(smb, X1_OFF, X2_OFF, bfr,
                                                    smf[RB_OFF/4 + co], 8 * h, shift);
            if (h == 1) loadB16(bfr, wsbf, rwg, useWs, 1, co, g);   // L0 frags dead now
            __syncthreads();
        }
    }

    // ---- conv3..6; next layer's B-frags load before each barrier ----
    convL<8, 8, 16, X2_STR, X3_STR, false>(smb, X2_OFF, X3_OFF, bfr, smf[RB_OFF/4 + 32 + co], 0, 0);
    loadB16(bfr, wsbf, rwg, useWs, 2, co, g);
    __syncthreads();

    convL<4, 4, 8, X3_STR, X4_STR, false>(smb, X3_OFF, X4_OFF, bfr, smf[RB_OFF/4 + 64 + co], 0, 0);
    loadB16(bfr, wsbf, rwg, useWs, 3, co, g);
    __syncthreads();

    convL<2, 2, 4, X4_STR, X5_STR, false>(smb, X4_OFF, X5_OFF, bfr, smf[RB_OFF/4 + 96 + co], 0, 0);
    loadB16(bfr, wsbf, rwg, useWs, 4, co, g);
    __syncthreads();

    convL<1, 1, 2, X5_STR, 0, true>(smb, X5_OFF, X6_OFF, bfr, smf[RB_OFF/4 + 128 + co], 0, 0);
    __syncthreads();

    // ---- head: wave 0 dot(X6, pw) + sigmoid ----
    if (w == 0) {
        float v = (l < 32) ? smf[X6_OFF/4 + l] * smf[PW_OFF/4 + l] : 0.f;
#pragma unroll
        for (int d = 32; d >= 1; d >>= 1) v += __shfl_xor(v, d, 64);
        if (l == 0) {
            const float z = smf[PBI_OFF/4] + v;
            out[branch * B + s] = 1.f / (1.f + expf(-z));
        }
    }
}

extern "C" void kernel_launch(void* const* d_in, const int* in_sizes, int n_in,
                              void* d_out, int out_size, void* d_ws, size_t ws_size,
                              hipStream_t stream) {
    const int*   user     = (const int*)d_in[0];
    const int*   item_pos = (const int*)d_in[1];
    const int*   item_neg = (const int*)d_in[2];
    const float* uemb     = (const float*)d_in[3];
    const float* iemb     = (const float*)d_in[4];
    const float* w1       = (const float*)d_in[5];
    const float* b1       = (const float*)d_in[6];
    const float* rw       = (const float*)d_in[7];
    const float* rb       = (const float*)d_in[8];
    const float* pw       = (const float*)d_in[9];
    const float* pb       = (const float*)d_in[10];
    float* out = (float*)d_out;
    const int B = in_sizes[0];   // 4096

    const int useWs = (ws_size >= 81920u * sizeof(unsigned short)) ? 1 : 0;
    unsigned short* wsbf = (unsigned short*)d_ws;
    if (useWs)
        preconv_w<<<dim3(320), dim3(256), 0, stream>>>(rw, wsbf);

    (void)hipFuncSetAttribute((const void*)convncf_main,
                              hipFuncAttributeMaxDynamicSharedMemorySize, SMEM_BYTES);
    dim3 grid(B, 2);
    convncf_main<<<grid, NT, SMEM_BYTES, stream>>>(
        user, item_pos, item_neg, uemb, iemb, w1, b1, rw, rb, pw, pb,
        wsbf, useWs, out, B);
}

// Round 12
// 340.701 us; speedup vs baseline: 1.1750x; 1.1750x over previous
//
#include <hip/hip_runtime.h>
#include <math.h>

#define NT 256
#define NW 4

typedef __attribute__((ext_vector_type(8))) short short8;
typedef __attribute__((ext_vector_type(4))) float f32x4;

// ---- LDS arena byte offsets (total 53,264 B; 3 blocks/CU if VGPR <= 128) ----
#define U_OFF    0        // 64 f32
#define IT_OFF   256      // 64 f32
#define B1_OFF   512      // 32 f32
#define RB_OFF   640      // 160 f32
#define PW_OFF   1280     // 32 f32
#define PBI_OFF  1408     // 1 f32
#define ZP_OFF   1424     // 64 B zero page (predicated out-of-range reads land here)
#define X1_OFF   1536     // bf16 [17][32][32] stride 2064 -> 35088 (two-half strip of conv1 out)
#define X1_STR   2064
#define X2_OFF   36624    // bf16 [16][16][32] stride 1040 -> 16640 -> end 53264
#define X2_STR   1040
#define X3_OFF   X1_OFF   // alias over X1 (dead after conv2b): bf16 [8][8][32] stride 528
#define X3_STR   528
#define X4_OFF   (X1_OFF + 4224)   // bf16 [4][4][32] stride 272 -> 1088
#define X4_STR   272
#define X5_OFF   (X1_OFF + 5312)   // bf16 [2][2][32] stride 144 -> 288
#define X5_STR   144
#define X6_OFF   (X1_OFF + 5600)   // 32 f32 = 128
#define SMEM_BYTES 53264
// R11 lesson: launch_bounds(256,3) -> compiler squeezed to 84 VGPR, demand ~160
// -> 0.64 GB/dispatch spill traffic. HW wave budget ~512 VGPR/SIMD in coarse
// granules => 3 waves/SIMD needs <=128 total. R12: cap stays 256 (never spill),
// natural demand cut to ~120 by LIVE-RANGE scheduling: bfr (64 regs) first
// written AFTER P2(h=0), so it never co-resides with the full P2 working set.
// HW then discovers 3 blocks/CU on its own iff allocator lands <=128.
// All X accesses swizzled: byte_bit4 ^= buffer_row_bit3; OOB taps -> zero page.

__device__ __forceinline__ unsigned short f2bf(float f) {   // RNE f32->bf16
    unsigned int x = __float_as_uint(f);
    x += 0x7fffu + ((x >> 16) & 1u);
    return (unsigned short)(x >> 16);
}

// B-frags for mfma_f32_16x16x32_bf16 (VERIFIED mapping, Round 2):
// lane l: col n=l&15 (co = nt*16+n), k = (l>>4)*8 + e.  ws: bf16 [L][tap][co][ci].
__device__ __forceinline__ void loadB16(short8 bfr[16], const unsigned short* __restrict__ wsbf,
                                        const float* __restrict__ rwg, int useWs,
                                        int L, int co, int g) {
    if (useWs) {
        const unsigned short* base = wsbf + L * 16384 + co * 32 + g * 8;
#pragma unroll
        for (int tap = 0; tap < 16; ++tap)
            bfr[tap] = *(const short8*)(base + tap * 1024);
    } else {  // fallback: gather f32 weights from rwg [L][co][ci][tap], convert in regs
#pragma unroll
        for (int tap = 0; tap < 16; ++tap) {
            union { short8 s; unsigned short u[8]; } cv;
#pragma unroll
            for (int e = 0; e < 8; ++e)
                cv.u[e] = f2bf(rwg[((L * 32 + co) * 32 + g * 8 + e) * 16 + tap]);
            bfr[tap] = cv.s;
        }
    }
}

// One conv layer as 16 tap-GEMMs via mfma_f32_16x16x32_bf16 (Round-2-verified
// mappings). Output PH x QW spatial block (rows offset by p0), m = q*PH + p.
// Input: logical NIN x NIN halo-free tensor; buffer row = logical row - shift.
// Out-of-range taps read the zero page. All addrs swizzled: bit4 ^= row bit3.
template<int PH, int QW, int NIN, int INS, int OUTS, bool LAST>
__device__ __forceinline__ void convL(char* smb, int inOff, int outOff,
                                      const short8 bfr[16], float bias,
                                      int p0, int shift) {
    const int t = threadIdx.x;
    const int w = t >> 6, l = t & 63;
    const int n = l & 15, g = l >> 4, nt = w & 1;
    constexpr int M = PH * QW;
    constexpr int MT = (M + 15) / 16;
    for (int tile = w; tile < 2 * MT; tile += NW) {   // step NW (even) keeps tile&1 == nt
        const int mt = tile >> 1;
        f32x4 acc = {bias, bias, bias, bias};
        const int m = mt * 16 + (l & 15);
        const int mm = (m < M) ? m : 0;
        const int p = mm % PH, q = mm / PH;
#pragma unroll
        for (int a = 0; a < 4; ++a)
#pragma unroll
            for (int dj = 0; dj < 4; ++dj) {
                const int row = 2 * (p0 + p) + a - 1;       // logical coords
                const int col = 2 * q + dj - 1;
                const bool ok = (m < M) && ((unsigned)row < (unsigned)NIN)
                                        && ((unsigned)col < (unsigned)NIN);
                const int rb = row - shift;                  // buffer row
                unsigned addr = (unsigned)(inOff + rb * INS + col * 64 + g * 16);
                addr ^= (unsigned)(((rb >> 3) & 1) << 4);
                addr = ok ? addr : (unsigned)(ZP_OFF + g * 16);
                short8 af = *(const short8*)(smb + addr);
                acc = __builtin_amdgcn_mfma_f32_16x16x32_bf16(af, bfr[a * 4 + dj], acc, 0, 0, 0);
            }
#pragma unroll
        for (int vi = 0; vi < 4; ++vi) {                     // D: col=l&15, row=g*4+vi
            const int mo = mt * 16 + g * 4 + vi;
            if (mo < M) {
                const float v = fmaxf(acc[vi], 0.f);
                if constexpr (LAST) {                        // M==1: only mo==0 lands here
                    *(float*)(smb + outOff + (nt * 16 + n) * 4) = v;
                } else {
                    const int po = mo % PH + p0, qo = mo / PH;
                    unsigned addr = (unsigned)(outOff + po * OUTS + qo * 64 + (nt * 16 + n) * 2);
                    addr ^= (unsigned)(((po >> 3) & 1) << 4);
                    *(unsigned short*)(smb + addr) = f2bf(v);
                }
            }
        }
    }
}

// pre-convert rest_w (f32 [L][co][ci][a][dj]) -> d_ws bf16 [L][tap][co][ci]
__global__ void preconv_w(const float* __restrict__ rwg, unsigned short* __restrict__ wsbf) {
    int idx = blockIdx.x * 256 + threadIdx.x;
    if (idx < 81920) {
        int ci = idx & 31, co = (idx >> 5) & 31, tap = (idx >> 10) & 15, L = idx >> 14;
        wsbf[idx] = f2bf(rwg[(((L * 32 + co) * 32 + ci) << 4) + tap]);
    }
}

__global__ void __launch_bounds__(NT, 2)
convncf_main(const int* __restrict__ user, const int* __restrict__ item_pos,
             const int* __restrict__ item_neg,
             const float* __restrict__ uemb, const float* __restrict__ iemb,
             const float* __restrict__ w1g, const float* __restrict__ b1g,
             const float* __restrict__ rwg, const float* __restrict__ rbg,
             const float* __restrict__ pwg, const float* __restrict__ pbg,
             const unsigned short* __restrict__ wsbf, int useWs,
             float* __restrict__ out, int B)
{
    extern __shared__ char smb[];
    float* smf = (float*)smb;
    const int t = threadIdx.x, w = t >> 6, l = t & 63;
    const int co = ((t >> 6) & 1) * 16 + (t & 15);   // this thread's output channel
    const int g = l >> 4;
    const int s = blockIdx.x, branch = blockIdx.y;
    const int uidx = user[s];
    const int iidx = branch ? item_neg[s] : item_pos[s];

    short8 bfr[16];   // first WRITTEN after P2(h=0) -> short live range (reg budget)

    // ---- P0: consts + embeddings + zero page (strided loop: 353 items) ----
    for (int i = t; i < 353; i += NT) {
        if (i < 64)       smf[U_OFF/4 + i]        = uemb[(long)uidx * 64 + i];
        else if (i < 128) smf[IT_OFF/4 + i - 64]  = iemb[(long)iidx * 64 + i - 64];
        else if (i < 160) smf[B1_OFF/4 + i - 128] = b1g[i - 128];
        else if (i < 320) smf[RB_OFF/4 + i - 160] = rbg[i - 160];
        else if (i < 352) smf[PW_OFF/4 + i - 320] = pwg[i - 320];
        else              smf[PBI_OFF/4] = pbg[0];
    }
    if (t < 4) *(float4*)(smb + ZP_OFF + t * 16) = make_float4(0.f, 0.f, 0.f, 0.f);
    __syncthreads();

    // ---- P2+conv2, two half-strips. Thread owns (jp, cgp); its T-slice
    //      tval[a][e] = sum_dj w1[cgp*8+e][a][dj] * it_pad[2jp-1+dj] computed
    //      directly from global w1 (L2-resident) — no T staging in LDS. ----
    {
        const int pi = t & 127;
        const int cgp = pi & 3, jp = pi >> 2;        // this thread's (col j, chan group)
        const int rlh = t >> 7;                      // row-half: 0 -> rl 0..8, 1 -> rl 9..16
        const int rl0 = rlh ? 9 : 0;
        const int rl1 = rlh ? 17 : 9;

        float tval[4][8];                            // T[a][jp][cgp*8+e], in regs
        {
            float itv[4];                            // item taps with pad guards (scoped)
#pragma unroll
            for (int dj = 0; dj < 4; ++dj) {
                const int c = 2 * jp - 1 + dj;
                itv[dj] = (c >= 0 && c < 64) ? smf[IT_OFF/4 + c] : 0.f;
            }
#pragma unroll
            for (int e = 0; e < 8; ++e) {
                const float* wp = w1g + (cgp * 8 + e) * 16;
#pragma unroll
                for (int a = 0; a < 4; ++a) {
                    const float4 wv = *(const float4*)(wp + a * 4);
                    float v = wv.x * itv[0];
                    v = fmaf(wv.y, itv[1], v);
                    v = fmaf(wv.z, itv[2], v);
                    v = fmaf(wv.w, itv[3], v);
                    tval[a][e] = v;
                }
            }
        }

        // ---- h = 0: P2 rows (shift 0), then conv2 rows 0..7 ----
        {
            float bb[8];                             // bias, scoped per half
            {
                const float* b1p = smf + B1_OFF/4 + cgp * 8;
#pragma unroll
                for (int e = 0; e < 8; ++e) bb[e] = b1p[e];
            }
            for (int rl = rl0; rl < rl1; ++rl) {
                float acc[8];
#pragma unroll
                for (int e = 0; e < 8; ++e) acc[e] = bb[e];
#pragma unroll
                for (int a = 0; a < 4; ++a) {
                    const int m = 2 * rl - 1 + a;
                    const float uv = (m >= 0) ? smf[U_OFF/4 + m] : 0.f;   // m <= 35 < 64
#pragma unroll
                    for (int e = 0; e < 8; ++e)
                        acc[e] = fmaf(uv, tval[a][e], acc[e]);
                }
                union { short8 sv; unsigned short u[8]; } cv;
#pragma unroll
                for (int e = 0; e < 8; ++e) cv.u[e] = f2bf(fmaxf(acc[e], 0.f));
                unsigned addr = (unsigned)(X1_OFF + rl * X1_STR + jp * 64 + cgp * 16);
                addr ^= (unsigned)(((rl >> 3) & 1) << 4);
                *(short8*)(smb + addr) = cv.sv;
            }
        }
        loadB16(bfr, wsbf, rwg, useWs, 0, co, g);   // conv2 weights: bfr live starts HERE
        __syncthreads();

        convL<8, 16, 32, X1_STR, X2_STR, false>(smb, X1_OFF, X2_OFF, bfr,
                                                smf[RB_OFF/4 + co], 0, 0);
        __syncthreads();

        // ---- h = 1: P2 rows (shift 15), then conv2 rows 8..15 ----
        {
            float bb[8];
            {
                const float* b1p = smf + B1_OFF/4 + cgp * 8;
#pragma unroll
                for (int e = 0; e < 8; ++e) bb[e] = b1p[e];
            }
            for (int rl = rl0; rl < rl1; ++rl) {
                const int r = rl + 15;
                float acc[8];
#pragma unroll
                for (int e = 0; e < 8; ++e) acc[e] = bb[e];
#pragma unroll
                for (int a = 0; a < 4; ++a) {
                    const int m = 2 * r - 1 + a;
                    const float uv = (m < 64) ? smf[U_OFF/4 + m] : 0.f;   // m >= 29 > 0
#pragma unroll
                    for (int e = 0; e < 8; ++e)
                        acc[e] = fmaf(uv, tval[a][e], acc[e]);
                }
                union { short8 sv; unsigned short u[8]; } cv;
#pragma unroll
                for (int e = 0; e < 8; ++e) cv.u[e] = f2bf(fmaxf(acc[e], 0.f));
                unsigned addr = (unsigned)(X1_OFF + rl * X1_STR + jp * 64 + cgp * 16);
                addr ^= (unsigned)(((rl >> 3) & 1) << 4);
                *(short8*)(smb + addr) = cv.sv;
            }
        }
        __syncthreads();

        convL<8, 16, 32, X1_STR, X2_STR, false>(smb, X1_OFF, X2_OFF, bfr,
                                                smf[RB_OFF/4 + co], 8, 15);
        loadB16(bfr, wsbf, rwg, useWs, 1, co, g);   // L0 frags dead now
        __syncthreads();
    }

    // ---- conv3..6; next layer's B-frags load before each barrier ----
    convL<8, 8, 16, X2_STR, X3_STR, false>(smb, X2_OFF, X3_OFF, bfr, smf[RB_OFF/4 + 32 + co], 0, 0);
    loadB16(bfr, wsbf, rwg, useWs, 2, co, g);
    __syncthreads();

    convL<4, 4, 8, X3_STR, X4_STR, false>(smb, X3_OFF, X4_OFF, bfr, smf[RB_OFF/4 + 64 + co], 0, 0);
    loadB16(bfr, wsbf, rwg, useWs, 3, co, g);
    __syncthreads();

    convL<2, 2, 4, X4_STR, X5_STR, false>(smb, X4_OFF, X5_OFF, bfr, smf[RB_OFF/4 + 96 + co], 0, 0);
    loadB16(bfr, wsbf, rwg, useWs, 4, co, g);
    __syncthreads();

    convL<1, 1, 2, X5_STR, 0, true>(smb, X5_OFF, X6_OFF, bfr, smf[RB_OFF/4 + 128 + co], 0, 0);
    __syncthreads();

    // ---- head: wave 0 dot(X6, pw) + sigmoid ----
    if (w == 0) {
        float v = (l < 32) ? smf[X6_OFF/4 + l] * smf[PW_OFF/4 + l] : 0.f;
#pragma unroll
        for (int d = 32; d >= 1; d >>= 1) v += __shfl_xor(v, d, 64);
        if (l == 0) {
            const float z = smf[PBI_OFF/4] + v;
            out[branch * B + s] = 1.f / (1.f + expf(-z));
        }
    }
}

extern "C" void kernel_launch(void* const* d_in, const int* in_sizes, int n_in,
                              void* d_out, int out_size, void* d_ws, size_t ws_size,
                              hipStream_t stream) {
    const int*   user     = (const int*)d_in[0];
    const int*   item_pos = (const int*)d_in[1];
    const int*   item_neg = (const int*)d_in[2];
    const float* uemb     = (const float*)d_in[3];
    const float* iemb     = (const float*)d_in[4];
    const float* w1       = (const float*)d_in[5];
    const float* b1       = (const float*)d_in[6];
    const float* rw       = (const float*)d_in[7];
    const float* rb       = (const float*)d_in[8];
    const float* pw       = (const float*)d_in[9];
    const float* pb       = (const float*)d_in[10];
    float* out = (float*)d_out;
    const int B = in_sizes[0];   // 4096

    const int useWs = (ws_size >= 81920u * sizeof(unsigned short)) ? 1 : 0;
    unsigned short* wsbf = (unsigned short*)d_ws;
    if (useWs)
        preconv_w<<<dim3(320), dim3(256), 0, stream>>>(rw, wsbf);

    (void)hipFuncSetAttribute((const void*)convncf_main,
                              hipFuncAttributeMaxDynamicSharedMemorySize, SMEM_BYTES);
    dim3 grid(B, 2);
    convncf_main<<<grid, NT, SMEM_BYTES, stream>>>(
        user, item_pos, item_neg, uemb, iemb, w1, b1, rw, rb, pw, pb,
        wsbf, useWs, out, B);
}

// Round 13
// 300.394 us; speedup vs baseline: 1.3327x; 1.1342x over previous
//
#include <hip/hip_runtime.h>
#include <math.h>

#define NT 256
#define NW 4

typedef __attribute__((ext_vector_type(8))) short short8;
typedef __attribute__((ext_vector_type(4))) float f32x4;

// ---- LDS arena byte offsets (total 53,264 B; 3 blocks/CU) ----
#define U_OFF    0        // 64 f32
#define IT_OFF   256      // 64 f32
#define B1_OFF   512      // 32 f32
#define RB_OFF   640      // 160 f32
#define PW_OFF   1280     // 32 f32
#define PBI_OFF  1408     // 1 f32
#define ZP_OFF   1424     // 64 B zero page (predicated out-of-range reads land here)
#define X1_OFF   1536     // bf16 [17][32][32] stride 2064 -> 35088 (two-half strip of conv1 out)
#define X1_STR   2064
#define X2_OFF   36624    // bf16 [16][16][32] stride 1040 -> 16640 -> end 53264
#define X2_STR   1040
#define X3_OFF   X1_OFF   // alias over X1 (dead after conv2b): bf16 [8][8][32] stride 528
#define X3_STR   528
#define X4_OFF   (X1_OFF + 4224)   // bf16 [4][4][32] stride 272 -> 1088
#define X4_STR   272
#define X5_OFF   (X1_OFF + 5312)   // bf16 [2][2][32] stride 144 -> 288
#define X5_STR   144
#define X6_OFF   (X1_OFF + 5600)   // 32 f32 = 128
#define SMEM_BYTES 53264
// Residency empirics (R7/R8/R11/R12): co-residency follows the DECLARED
// launch_bounds, and the cap it implies must cover natural demand or spill.
// R11: (256,3) -> 3 blocks/CU (33.7% occ) at this exact LDS, but demand ~160
// vs cap 84 -> 0.65 GB spill. R12: demand restructured to ~88 (bfr live-range
// starts after P2h0), (256,2) -> only 2 blocks. R13 = R12 code + (256,3):
// squeeze 88->~84 is 4-6 regs (scheduling slack, not scratch) + 3 blocks.
// All X accesses swizzled: byte_bit4 ^= buffer_row_bit3; OOB taps -> zero page.

__device__ __forceinline__ unsigned short f2bf(float f) {   // RNE f32->bf16
    unsigned int x = __float_as_uint(f);
    x += 0x7fffu + ((x >> 16) & 1u);
    return (unsigned short)(x >> 16);
}

// B-frags for mfma_f32_16x16x32_bf16 (VERIFIED mapping, Round 2):
// lane l: col n=l&15 (co = nt*16+n), k = (l>>4)*8 + e.  ws: bf16 [L][tap][co][ci].
__device__ __forceinline__ void loadB16(short8 bfr[16], const unsigned short* __restrict__ wsbf,
                                        const float* __restrict__ rwg, int useWs,
                                        int L, int co, int g) {
    if (useWs) {
        const unsigned short* base = wsbf + L * 16384 + co * 32 + g * 8;
#pragma unroll
        for (int tap = 0; tap < 16; ++tap)
            bfr[tap] = *(const short8*)(base + tap * 1024);
    } else {  // fallback: gather f32 weights from rwg [L][co][ci][tap], convert in regs
#pragma unroll
        for (int tap = 0; tap < 16; ++tap) {
            union { short8 s; unsigned short u[8]; } cv;
#pragma unroll
            for (int e = 0; e < 8; ++e)
                cv.u[e] = f2bf(rwg[((L * 32 + co) * 32 + g * 8 + e) * 16 + tap]);
            bfr[tap] = cv.s;
        }
    }
}

// One conv layer as 16 tap-GEMMs via mfma_f32_16x16x32_bf16 (Round-2-verified
// mappings). Output PH x QW spatial block (rows offset by p0), m = q*PH + p.
// Input: logical NIN x NIN halo-free tensor; buffer row = logical row - shift.
// Out-of-range taps read the zero page. All addrs swizzled: bit4 ^= row bit3.
template<int PH, int QW, int NIN, int INS, int OUTS, bool LAST>
__device__ __forceinline__ void convL(char* smb, int inOff, int outOff,
                                      const short8 bfr[16], float bias,
                                      int p0, int shift) {
    const int t = threadIdx.x;
    const int w = t >> 6, l = t & 63;
    const int n = l & 15, g = l >> 4, nt = w & 1;
    constexpr int M = PH * QW;
    constexpr int MT = (M + 15) / 16;
    for (int tile = w; tile < 2 * MT; tile += NW) {   // step NW (even) keeps tile&1 == nt
        const int mt = tile >> 1;
        f32x4 acc = {bias, bias, bias, bias};
        const int m = mt * 16 + (l & 15);
        const int mm = (m < M) ? m : 0;
        const int p = mm % PH, q = mm / PH;
#pragma unroll
        for (int a = 0; a < 4; ++a)
#pragma unroll
            for (int dj = 0; dj < 4; ++dj) {
                const int row = 2 * (p0 + p) + a - 1;       // logical coords
                const int col = 2 * q + dj - 1;
                const bool ok = (m < M) && ((unsigned)row < (unsigned)NIN)
                                        && ((unsigned)col < (unsigned)NIN);
                const int rb = row - shift;                  // buffer row
                unsigned addr = (unsigned)(inOff + rb * INS + col * 64 + g * 16);
                addr ^= (unsigned)(((rb >> 3) & 1) << 4);
                addr = ok ? addr : (unsigned)(ZP_OFF + g * 16);
                short8 af = *(const short8*)(smb + addr);
                acc = __builtin_amdgcn_mfma_f32_16x16x32_bf16(af, bfr[a * 4 + dj], acc, 0, 0, 0);
            }
#pragma unroll
        for (int vi = 0; vi < 4; ++vi) {                     // D: col=l&15, row=g*4+vi
            const int mo = mt * 16 + g * 4 + vi;
            if (mo < M) {
                const float v = fmaxf(acc[vi], 0.f);
                if constexpr (LAST) {                        // M==1: only mo==0 lands here
                    *(float*)(smb + outOff + (nt * 16 + n) * 4) = v;
                } else {
                    const int po = mo % PH + p0, qo = mo / PH;
                    unsigned addr = (unsigned)(outOff + po * OUTS + qo * 64 + (nt * 16 + n) * 2);
                    addr ^= (unsigned)(((po >> 3) & 1) << 4);
                    *(unsigned short*)(smb + addr) = f2bf(v);
                }
            }
        }
    }
}

// pre-convert rest_w (f32 [L][co][ci][a][dj]) -> d_ws bf16 [L][tap][co][ci]
__global__ void preconv_w(const float* __restrict__ rwg, unsigned short* __restrict__ wsbf) {
    int idx = blockIdx.x * 256 + threadIdx.x;
    if (idx < 81920) {
        int ci = idx & 31, co = (idx >> 5) & 31, tap = (idx >> 10) & 15, L = idx >> 14;
        wsbf[idx] = f2bf(rwg[(((L * 32 + co) * 32 + ci) << 4) + tap]);
    }
}

__global__ void __launch_bounds__(NT, 3)
convncf_main(const int* __restrict__ user, const int* __restrict__ item_pos,
             const int* __restrict__ item_neg,
             const float* __restrict__ uemb, const float* __restrict__ iemb,
             const float* __restrict__ w1g, const float* __restrict__ b1g,
             const float* __restrict__ rwg, const float* __restrict__ rbg,
             const float* __restrict__ pwg, const float* __restrict__ pbg,
             const unsigned short* __restrict__ wsbf, int useWs,
             float* __restrict__ out, int B)
{
    extern __shared__ char smb[];
    float* smf = (float*)smb;
    const int t = threadIdx.x, w = t >> 6, l = t & 63;
    const int co = ((t >> 6) & 1) * 16 + (t & 15);   // this thread's output channel
    const int g = l >> 4;
    const int s = blockIdx.x, branch = blockIdx.y;
    const int uidx = user[s];
    const int iidx = branch ? item_neg[s] : item_pos[s];

    short8 bfr[16];   // first WRITTEN after P2(h=0) -> short live range (reg budget)

    // ---- P0: consts + embeddings + zero page (strided loop: 353 items) ----
    for (int i = t; i < 353; i += NT) {
        if (i < 64)       smf[U_OFF/4 + i]        = uemb[(long)uidx * 64 + i];
        else if (i < 128) smf[IT_OFF/4 + i - 64]  = iemb[(long)iidx * 64 + i - 64];
        else if (i < 160) smf[B1_OFF/4 + i - 128] = b1g[i - 128];
        else if (i < 320) smf[RB_OFF/4 + i - 160] = rbg[i - 160];
        else if (i < 352) smf[PW_OFF/4 + i - 320] = pwg[i - 320];
        else              smf[PBI_OFF/4] = pbg[0];
    }
    if (t < 4) *(float4*)(smb + ZP_OFF + t * 16) = make_float4(0.f, 0.f, 0.f, 0.f);
    __syncthreads();

    // ---- P2+conv2, two half-strips. Thread owns (jp, cgp); its T-slice
    //      tval[a][e] = sum_dj w1[cgp*8+e][a][dj] * it_pad[2jp-1+dj] computed
    //      directly from global w1 (L2-resident) — no T staging in LDS. ----
    {
        const int pi = t & 127;
        const int cgp = pi & 3, jp = pi >> 2;        // this thread's (col j, chan group)
        const int rlh = t >> 7;                      // row-half: 0 -> rl 0..8, 1 -> rl 9..16
        const int rl0 = rlh ? 9 : 0;
        const int rl1 = rlh ? 17 : 9;

        float tval[4][8];                            // T[a][jp][cgp*8+e], in regs
        {
            float itv[4];                            // item taps with pad guards (scoped)
#pragma unroll
            for (int dj = 0; dj < 4; ++dj) {
                const int c = 2 * jp - 1 + dj;
                itv[dj] = (c >= 0 && c < 64) ? smf[IT_OFF/4 + c] : 0.f;
            }
#pragma unroll
            for (int e = 0; e < 8; ++e) {
                const float* wp = w1g + (cgp * 8 + e) * 16;
#pragma unroll
                for (int a = 0; a < 4; ++a) {
                    const float4 wv = *(const float4*)(wp + a * 4);
                    float v = wv.x * itv[0];
                    v = fmaf(wv.y, itv[1], v);
                    v = fmaf(wv.z, itv[2], v);
                    v = fmaf(wv.w, itv[3], v);
                    tval[a][e] = v;
                }
            }
        }

        // ---- h = 0: P2 rows (shift 0), then conv2 rows 0..7 ----
        {
            float bb[8];                             // bias, scoped per half
            {
                const float* b1p = smf + B1_OFF/4 + cgp * 8;
#pragma unroll
                for (int e = 0; e < 8; ++e) bb[e] = b1p[e];
            }
            for (int rl = rl0; rl < rl1; ++rl) {
                float acc[8];
#pragma unroll
                for (int e = 0; e < 8; ++e) acc[e] = bb[e];
#pragma unroll
                for (int a = 0; a < 4; ++a) {
                    const int m = 2 * rl - 1 + a;
                    const float uv = (m >= 0) ? smf[U_OFF/4 + m] : 0.f;   // m <= 35 < 64
#pragma unroll
                    for (int e = 0; e < 8; ++e)
                        acc[e] = fmaf(uv, tval[a][e], acc[e]);
                }
                union { short8 sv; unsigned short u[8]; } cv;
#pragma unroll
                for (int e = 0; e < 8; ++e) cv.u[e] = f2bf(fmaxf(acc[e], 0.f));
                unsigned addr = (unsigned)(X1_OFF + rl * X1_STR + jp * 64 + cgp * 16);
                addr ^= (unsigned)(((rl >> 3) & 1) << 4);
                *(short8*)(smb + addr) = cv.sv;
            }
        }
        loadB16(bfr, wsbf, rwg, useWs, 0, co, g);   // conv2 weights: bfr live starts HERE
        __syncthreads();

        convL<8, 16, 32, X1_STR, X2_STR, false>(smb, X1_OFF, X2_OFF, bfr,
                                                smf[RB_OFF/4 + co], 0, 0);
        __syncthreads();

        // ---- h = 1: P2 rows (shift 15), then conv2 rows 8..15 ----
        {
            float bb[8];
            {
                const float* b1p = smf + B1_OFF/4 + cgp * 8;
#pragma unroll
                for (int e = 0; e < 8; ++e) bb[e] = b1p[e];
            }
            for (int rl = rl0; rl < rl1; ++rl) {
                const int r = rl + 15;
                float acc[8];
#pragma unroll
                for (int e = 0; e < 8; ++e) acc[e] = bb[e];
#pragma unroll
                for (int a = 0; a < 4; ++a) {
                    const int m = 2 * r - 1 + a;
                    const float uv = (m < 64) ? smf[U_OFF/4 + m] : 0.f;   // m >= 29 > 0
#pragma unroll
                    for (int e = 0; e < 8; ++e)
                        acc[e] = fmaf(uv, tval[a][e], acc[e]);
                }
                union { short8 sv; unsigned short u[8]; } cv;
#pragma unroll
                for (int e = 0; e < 8; ++e) cv.u[e] = f2bf(fmaxf(acc[e], 0.f));
                unsigned addr = (unsigned)(X1_OFF + rl * X1_STR + jp * 64 + cgp * 16);
                addr ^= (unsigned)(((rl >> 3) & 1) << 4);
                *(short8*)(smb + addr) = cv.sv;
            }
        }
        __syncthreads();

        convL<8, 16, 32, X1_STR, X2_STR, false>(smb, X1_OFF, X2_OFF, bfr,
                                                smf[RB_OFF/4 + co], 8, 15);
        loadB16(bfr, wsbf, rwg, useWs, 1, co, g);   // L0 frags dead now
        __syncthreads();
    }

    // ---- conv3..6; next layer's B-frags load before each barrier ----
    convL<8, 8, 16, X2_STR, X3_STR, false>(smb, X2_OFF, X3_OFF, bfr, smf[RB_OFF/4 + 32 + co], 0, 0);
    loadB16(bfr, wsbf, rwg, useWs, 2, co, g);
    __syncthreads();

    convL<4, 4, 8, X3_STR, X4_STR, false>(smb, X3_OFF, X4_OFF, bfr, smf[RB_OFF/4 + 64 + co], 0, 0);
    loadB16(bfr, wsbf, rwg, useWs, 3, co, g);
    __syncthreads();

    convL<2, 2, 4, X4_STR, X5_STR, false>(smb, X4_OFF, X5_OFF, bfr, smf[RB_OFF/4 + 96 + co], 0, 0);
    loadB16(bfr, wsbf, rwg, useWs, 4, co, g);
    __syncthreads();

    convL<1, 1, 2, X5_STR, 0, true>(smb, X5_OFF, X6_OFF, bfr, smf[RB_OFF/4 + 128 + co], 0, 0);
    __syncthreads();

    // ---- head: wave 0 dot(X6, pw) + sigmoid ----
    if (w == 0) {
        float v = (l < 32) ? smf[X6_OFF/4 + l] * smf[PW_OFF/4 + l] : 0.f;
#pragma unroll
        for (int d = 32; d >= 1; d >>= 1) v += __shfl_xor(v, d, 64);
        if (l == 0) {
            const float z = smf[PBI_OFF/4] + v;
            out[branch * B + s] = 1.f / (1.f + expf(-z));
        }
    }
}

extern "C" void kernel_launch(void* const* d_in, const int* in_sizes, int n_in,
                              void* d_out, int out_size, void* d_ws, size_t ws_size,
                              hipStream_t stream) {
    const int*   user     = (const int*)d_in[0];
    const int*   item_pos = (const int*)d_in[1];
    const int*   item_neg = (const int*)d_in[2];
    const float* uemb     = (const float*)d_in[3];
    const float* iemb     = (const float*)d_in[4];
    const float* w1       = (const float*)d_in[5];
    const float* b1       = (const float*)d_in[6];
    const float* rw       = (const float*)d_in[7];
    const float* rb       = (const float*)d_in[8];
    const float* pw       = (const float*)d_in[9];
    const float* pb       = (const float*)d_in[10];
    float* out = (float*)d_out;
    const int B = in_sizes[0];   // 4096

    const int useWs = (ws_size >= 81920u * sizeof(unsigned short)) ? 1 : 0;
    unsigned short* wsbf = (unsigned short*)d_ws;
    if (useWs)
        preconv_w<<<dim3(320), dim3(256), 0, stream>>>(rw, wsbf);

    (void)hipFuncSetAttribute((const void*)convncf_main,
                              hipFuncAttributeMaxDynamicSharedMemorySize, SMEM_BYTES);
    dim3 grid(B, 2);
    convncf_main<<<grid, NT, SMEM_BYTES, stream>>>(
        user, item_pos, item_neg, uemb, iemb, w1, b1, rw, rb, pw, pb,
        wsbf, useWs, out, B);
}